// Round 2
// baseline (862.723 us; speedup 1.0000x reference)
//
#include <hip/hip_runtime.h>
#include <cstdint>
#include <cstddef>

#define BLK 256
#define DG 12
#define NSLOT 30   // 12 rbfL + normL + 12 rbfR + normR + d2L + idxL + d2R + idxR

static constexpr float SIGMA_ = 2.5f;
static constexpr float EPS_ = 0.01f;

// ---------------------------------------------------------------------------
// Kernel 1: partial scans. Thread = one query l; block.y = n-chunk s.
// Argmin path replicates the reference's fp32 cancellation formula
// (|q|^2 + |p|^2 - 2 q.p, BLAS-style fma dot, clamped at 0) so that
// near-tie rounding resolves identically to the np reference.
// ---------------------------------------------------------------------------
__global__ __launch_bounds__(BLK) void pip_partial(
    const float* __restrict__ locs_l, const float* __restrict__ locs_r,
    const float* __restrict__ g1_pos, const float* __restrict__ g2_pos,
    const float* __restrict__ s1_v,   const float* __restrict__ s1_x,
    const float* __restrict__ s2_v,   const float* __restrict__ s2_x,
    float* __restrict__ ws, int L, int N, int chunk)
{
#pragma clang fp contract(off)   // keep plain mul/add unfused; fma only where written
    const int l = blockIdx.x * BLK + threadIdx.x;
    const int s = blockIdx.y;
    const int lc = (l < L) ? l : (L - 1);

    const float qlx = locs_l[3 * lc + 0];
    const float qly = locs_l[3 * lc + 1];
    const float qlz = locs_l[3 * lc + 2];
    const float qrx = locs_r[3 * lc + 0];
    const float qry = locs_r[3 * lc + 1];
    const float qrz = locs_r[3 * lc + 2];

    // |q|^2 exactly as np.sum(a*a, -1): ((x*x + y*y) + z*z), no fma
    const float nqL = (qlx * qlx + qly * qly) + qlz * qlz;
    const float nqR = (qrx * qrx + qry * qry) + qrz * qrz;

    float aL[DG], aR[DG];
#pragma unroll
    for (int k = 0; k < DG; ++k) { aL[k] = 0.f; aR[k] = 0.f; }
    float nL = 0.f, nR = 0.f;
    float bdL = 3.4e38f, bdR = 3.4e38f;
    unsigned biL = 0u, biR = 0u;

    const float kinv = -1.0f / SIGMA_;   // exp(-d/sigma)

    const int n0 = s * chunk;
    const int n1 = (n0 + chunk < N) ? (n0 + chunk) : N;

#pragma unroll 2
    for (int n = n0; n < n1; ++n) {
        {   // argmin vs g1 (left) — reference trick formula, fp32
            const float px = g1_pos[3 * n + 0];
            const float py = g1_pos[3 * n + 1];
            const float pz = g1_pos[3 * n + 2];
            const float pn2 = (px * px + py * py) + pz * pz;
            const float dot = fmaf(qlz, pz, fmaf(qly, py, qlx * px));
            float d2 = (nqL + pn2) - 2.0f * dot;
            d2 = fmaxf(d2, 0.0f);                 // ref: max(d2, 0) before sqrt
            const bool c = d2 < bdL;
            bdL = c ? d2 : bdL;
            biL = c ? (unsigned)n : biL;
        }
        {   // argmin vs g2 (right)
            const float px = g2_pos[3 * n + 0];
            const float py = g2_pos[3 * n + 1];
            const float pz = g2_pos[3 * n + 2];
            const float pn2 = (px * px + py * py) + pz * pz;
            const float dot = fmaf(qrz, pz, fmaf(qry, py, qrx * px));
            float d2 = (nqR + pn2) - 2.0f * dot;
            d2 = fmaxf(d2, 0.0f);
            const bool c = d2 < bdR;
            bdR = c ? d2 : bdR;
            biR = c ? (unsigned)n : biR;
        }
        {   // RBF vs s1 (left) — smooth, direct form is fine
            const float px = s1_v[3 * n + 0];
            const float py = s1_v[3 * n + 1];
            const float pz = s1_v[3 * n + 2];
            const float dx = qlx - px, dy = qly - py, dz = qlz - pz;
            const float d2 = fmaf(dx, dx, fmaf(dy, dy, dz * dz));
            const float w = __expf(kinv * __builtin_amdgcn_sqrtf(d2));
            const float4* f = (const float4*)(s1_x + (size_t)n * DG);
            const float4 f0 = f[0], f1 = f[1], f2 = f[2];
            aL[0] = fmaf(w, f0.x, aL[0]);  aL[1]  = fmaf(w, f0.y, aL[1]);
            aL[2] = fmaf(w, f0.z, aL[2]);  aL[3]  = fmaf(w, f0.w, aL[3]);
            aL[4] = fmaf(w, f1.x, aL[4]);  aL[5]  = fmaf(w, f1.y, aL[5]);
            aL[6] = fmaf(w, f1.z, aL[6]);  aL[7]  = fmaf(w, f1.w, aL[7]);
            aL[8] = fmaf(w, f2.x, aL[8]);  aL[9]  = fmaf(w, f2.y, aL[9]);
            aL[10] = fmaf(w, f2.z, aL[10]); aL[11] = fmaf(w, f2.w, aL[11]);
            nL += w;
        }
        {   // RBF vs s2 (right)
            const float px = s2_v[3 * n + 0];
            const float py = s2_v[3 * n + 1];
            const float pz = s2_v[3 * n + 2];
            const float dx = qrx - px, dy = qry - py, dz = qrz - pz;
            const float d2 = fmaf(dx, dx, fmaf(dy, dy, dz * dz));
            const float w = __expf(kinv * __builtin_amdgcn_sqrtf(d2));
            const float4* f = (const float4*)(s2_x + (size_t)n * DG);
            const float4 f0 = f[0], f1 = f[1], f2 = f[2];
            aR[0] = fmaf(w, f0.x, aR[0]);  aR[1]  = fmaf(w, f0.y, aR[1]);
            aR[2] = fmaf(w, f0.z, aR[2]);  aR[3]  = fmaf(w, f0.w, aR[3]);
            aR[4] = fmaf(w, f1.x, aR[4]);  aR[5]  = fmaf(w, f1.y, aR[5]);
            aR[6] = fmaf(w, f1.z, aR[6]);  aR[7]  = fmaf(w, f1.w, aR[7]);
            aR[8] = fmaf(w, f2.x, aR[8]);  aR[9]  = fmaf(w, f2.y, aR[9]);
            aR[10] = fmaf(w, f2.z, aR[10]); aR[11] = fmaf(w, f2.w, aR[11]);
            nR += w;
        }
    }

    if (l < L) {
        float* p = ws + (size_t)(s * NSLOT) * (size_t)L + (size_t)l;
#pragma unroll
        for (int k = 0; k < DG; ++k) p[(size_t)k * L] = aL[k];
        p[(size_t)DG * L] = nL;
#pragma unroll
        for (int k = 0; k < DG; ++k) p[(size_t)(13 + k) * L] = aR[k];
        p[(size_t)25 * L] = nR;
        unsigned* pu = (unsigned*)p;
        pu[(size_t)26 * L] = __float_as_uint(bdL);   // d2 >= 0 -> bit-ordered
        pu[(size_t)27 * L] = biL;
        pu[(size_t)28 * L] = __float_as_uint(bdR);
        pu[(size_t)29 * L] = biR;
    }
}

__device__ __forceinline__ float tanh_pos(float x) {
    // x > 0 always (norm >= eps). exp underflow -> t=0 -> 1.0 (correct limit).
    const float t = __expf(-2.f * x);
    return (1.f - t) / (1.f + t);
}

// ---------------------------------------------------------------------------
// Kernel 2: reduce partials across S chunks, gather nearest-node feats,
// run the 50->50->1 MLP. Thread = one query l.
// ---------------------------------------------------------------------------
__global__ __launch_bounds__(BLK) void pip_reduce(
    const float* __restrict__ ws,
    const float* __restrict__ g1_x, const float* __restrict__ g2_x,
    const float* __restrict__ W1, const float* __restrict__ b1,
    const float* __restrict__ W2, const float* __restrict__ b2,
    float* __restrict__ out, int L, int S)
{
#pragma clang fp contract(off)
    const int l = blockIdx.x * BLK + threadIdx.x;
    if (l >= L) return;

    float aL[DG + 1], aR[DG + 1];
#pragma unroll
    for (int k = 0; k <= DG; ++k) { aL[k] = 0.f; aR[k] = 0.f; }
    unsigned long long keyL = ~0ull, keyR = ~0ull;

    for (int s = 0; s < S; ++s) {
        const float* p = ws + (size_t)(s * NSLOT) * (size_t)L + (size_t)l;
#pragma unroll
        for (int k = 0; k <= DG; ++k) aL[k] += p[(size_t)k * L];
#pragma unroll
        for (int k = 0; k <= DG; ++k) aR[k] += p[(size_t)(13 + k) * L];
        const unsigned* pu = (const unsigned*)p;
        const unsigned dL = pu[(size_t)26 * L];
        const unsigned iL = pu[(size_t)27 * L];
        const unsigned dR = pu[(size_t)28 * L];
        const unsigned iR = pu[(size_t)29 * L];
        const unsigned long long cL = ((unsigned long long)dL << 32) | (unsigned long long)iL;
        const unsigned long long cR = ((unsigned long long)dR << 32) | (unsigned long long)iR;
        keyL = cL < keyL ? cL : keyL;
        keyR = cR < keyR ? cR : keyR;
    }

    const unsigned idxL = (unsigned)(keyL & 0xffffffffull);
    const unsigned idxR = (unsigned)(keyR & 0xffffffffull);
    const float normL = aL[DG] + EPS_;
    const float normR = aR[DG] + EPS_;

    // x[50] = [g1_x[idxL] (12), rbfL/normL (12), tanh(normL),
    //          g2_x[idxR] (12), rbfR/normR (12), tanh(normR)]
    float x[50];
    {
        const float4* f = (const float4*)(g1_x + (size_t)idxL * DG);
        const float4 f0 = f[0], f1 = f[1], f2 = f[2];
        x[0] = f0.x; x[1] = f0.y; x[2]  = f0.z; x[3]  = f0.w;
        x[4] = f1.x; x[5] = f1.y; x[6]  = f1.z; x[7]  = f1.w;
        x[8] = f2.x; x[9] = f2.y; x[10] = f2.z; x[11] = f2.w;
    }
#pragma unroll
    for (int k = 0; k < DG; ++k) x[12 + k] = aL[k] / normL;
    x[24] = tanh_pos(normL);
    {
        const float4* f = (const float4*)(g2_x + (size_t)idxR * DG);
        const float4 f0 = f[0], f1 = f[1], f2 = f[2];
        x[25] = f0.x; x[26] = f0.y; x[27] = f0.z; x[28] = f0.w;
        x[29] = f1.x; x[30] = f1.y; x[31] = f1.z; x[32] = f1.w;
        x[33] = f2.x; x[34] = f2.y; x[35] = f2.z; x[36] = f2.w;
    }
#pragma unroll
    for (int k = 0; k < DG; ++k) x[37 + k] = aR[k] / normR;
    x[49] = tanh_pos(normR);

    // MLP: h = relu(x @ W1 + b1); out = h @ W2 + b2
    float h[50];
#pragma unroll
    for (int j = 0; j < 50; ++j) h[j] = b1[j];
#pragma unroll
    for (int k = 0; k < 50; ++k) {
        const float xk = x[k];
#pragma unroll
        for (int j = 0; j < 50; ++j) h[j] = fmaf(xk, W1[k * 50 + j], h[j]);
    }
    float o = b2[0];
#pragma unroll
    for (int j = 0; j < 50; ++j) o = fmaf(fmaxf(h[j], 0.f), W2[j], o);
    out[l] = o;
}

// ---------------------------------------------------------------------------
extern "C" void kernel_launch(void* const* d_in, const int* in_sizes, int n_in,
                              void* d_out, int out_size, void* d_ws, size_t ws_size,
                              hipStream_t stream) {
    const float* locs_l = (const float*)d_in[0];
    const float* locs_r = (const float*)d_in[1];
    const float* g1_pos = (const float*)d_in[2];
    const float* g1_x   = (const float*)d_in[3];
    const float* g2_pos = (const float*)d_in[4];
    const float* g2_x   = (const float*)d_in[5];
    const float* s1_v   = (const float*)d_in[6];
    const float* s1_x   = (const float*)d_in[7];
    const float* s2_v   = (const float*)d_in[8];
    const float* s2_x   = (const float*)d_in[9];
    const float* W1     = (const float*)d_in[10];
    const float* b1     = (const float*)d_in[11];
    const float* W2     = (const float*)d_in[12];
    const float* b2     = (const float*)d_in[13];
    float* out = (float*)d_out;
    float* ws  = (float*)d_ws;

    const int L = in_sizes[0] / 3;   // 4096
    const int N = in_sizes[2] / 3;   // 40000

    // n-split count: want 32 (2048 waves -> 2/SIMD), capped by workspace size.
    int S = 32;
    const size_t bytes_per_split = (size_t)NSLOT * (size_t)L * sizeof(float);
    while (S > 1 && (size_t)S * bytes_per_split > ws_size) S >>= 1;
    const int chunk = (N + S - 1) / S;

    const int lblocks = (L + BLK - 1) / BLK;
    dim3 grid1(lblocks, S);
    pip_partial<<<grid1, dim3(BLK), 0, stream>>>(
        locs_l, locs_r, g1_pos, g2_pos, s1_v, s1_x, s2_v, s2_x, ws, L, N, chunk);

    pip_reduce<<<dim3(lblocks), dim3(BLK), 0, stream>>>(
        ws, g1_x, g2_x, W1, b1, W2, b2, out, L, S);
}

// Round 3
// 520.644 us; speedup vs baseline: 1.6570x; 1.6570x over previous
//
#include <hip/hip_runtime.h>
#include <cstdint>
#include <cstddef>

#define BLK 256
#define DG 12
#define NSLOT 30   // 12 rbfL + normL + 12 rbfR + normR + d2L + idxL + d2R + idxR

static constexpr float SIGMA_ = 2.5f;
static constexpr float EPS_ = 0.01f;
// exp(-d/sigma) == exp2(c2 * d), c2 = -1/(sigma*ln2)
static constexpr float C2_ = -0.57707801635558534f;

// ---------------------------------------------------------------------------
// Kernel 0: precompute |p|^2 for g1_pos/g2_pos (exact ref arithmetic:
// ((x*x + y*y) + z*z), no fma contraction).
// ---------------------------------------------------------------------------
__global__ __launch_bounds__(BLK) void pip_pn2(
    const float* __restrict__ g1_pos, const float* __restrict__ g2_pos,
    float* __restrict__ pn2, int N)
{
#pragma clang fp contract(off)
    const int i = blockIdx.x * BLK + threadIdx.x;
    if (i < N) {
        const float x = g1_pos[3 * i], y = g1_pos[3 * i + 1], z = g1_pos[3 * i + 2];
        pn2[i] = (x * x + y * y) + z * z;
    } else if (i < 2 * N) {
        const int j = i - N;
        const float x = g2_pos[3 * j], y = g2_pos[3 * j + 1], z = g2_pos[3 * j + 2];
        pn2[i] = (x * x + y * y) + z * z;
    }
}

// ---------------------------------------------------------------------------
// Kernel 1: partial scans. Thread = one query l; block.y = n-chunk s.
// Argmin path replicates the reference's fp32 cancellation formula
// (|q|^2 + |p|^2 - 2 q.p, fma dot chain, clamped at 0).
// ---------------------------------------------------------------------------
__global__ __launch_bounds__(BLK) void pip_partial(
    const float* __restrict__ locs_l, const float* __restrict__ locs_r,
    const float* __restrict__ g1_pos, const float* __restrict__ g2_pos,
    const float* __restrict__ s1_v,   const float* __restrict__ s1_x,
    const float* __restrict__ s2_v,   const float* __restrict__ s2_x,
    const float* __restrict__ pn2_1,  const float* __restrict__ pn2_2,
    float* __restrict__ part, int L, int N, int chunk)
{
#pragma clang fp contract(off)   // plain mul/add stay unfused; fma only where written
    const int l = blockIdx.x * BLK + threadIdx.x;
    const int s = blockIdx.y;
    const int lc = (l < L) ? l : (L - 1);

    const float qlx = locs_l[3 * lc + 0];
    const float qly = locs_l[3 * lc + 1];
    const float qlz = locs_l[3 * lc + 2];
    const float qrx = locs_r[3 * lc + 0];
    const float qry = locs_r[3 * lc + 1];
    const float qrz = locs_r[3 * lc + 2];

    const float nqL = (qlx * qlx + qly * qly) + qlz * qlz;
    const float nqR = (qrx * qrx + qry * qry) + qrz * qrz;

    float aL[DG], aR[DG];
#pragma unroll
    for (int k = 0; k < DG; ++k) { aL[k] = 0.f; aR[k] = 0.f; }
    float nL = 0.f, nR = 0.f;
    float bdL = 3.4e38f, bdR = 3.4e38f;
    unsigned biL = 0u, biR = 0u;

    const int n0 = s * chunk;
    const int n1 = (n0 + chunk < N) ? (n0 + chunk) : N;

#pragma unroll 4
    for (int n = n0; n < n1; ++n) {
        {   // argmin vs g1 (left)
            const float px = g1_pos[3 * n + 0];
            const float py = g1_pos[3 * n + 1];
            const float pz = g1_pos[3 * n + 2];
            const float dot = fmaf(qlz, pz, fmaf(qly, py, qlx * px));
            float d2 = (nqL + pn2_1[n]) - 2.0f * dot;
            d2 = fmaxf(d2, 0.0f);
            const bool c = d2 < bdL;
            bdL = c ? d2 : bdL;
            biL = c ? (unsigned)n : biL;
        }
        {   // argmin vs g2 (right)
            const float px = g2_pos[3 * n + 0];
            const float py = g2_pos[3 * n + 1];
            const float pz = g2_pos[3 * n + 2];
            const float dot = fmaf(qrz, pz, fmaf(qry, py, qrx * px));
            float d2 = (nqR + pn2_2[n]) - 2.0f * dot;
            d2 = fmaxf(d2, 0.0f);
            const bool c = d2 < bdR;
            bdR = c ? d2 : bdR;
            biR = c ? (unsigned)n : biR;
        }
        {   // RBF vs s1 (left)
            const float px = s1_v[3 * n + 0];
            const float py = s1_v[3 * n + 1];
            const float pz = s1_v[3 * n + 2];
            const float dx = qlx - px, dy = qly - py, dz = qlz - pz;
            const float d2 = fmaf(dx, dx, fmaf(dy, dy, dz * dz));
            const float w = __builtin_amdgcn_exp2f(C2_ * __builtin_amdgcn_sqrtf(d2));
            const float4* f = (const float4*)(s1_x + (size_t)n * DG);
            const float4 f0 = f[0], f1 = f[1], f2 = f[2];
            aL[0] = fmaf(w, f0.x, aL[0]);  aL[1]  = fmaf(w, f0.y, aL[1]);
            aL[2] = fmaf(w, f0.z, aL[2]);  aL[3]  = fmaf(w, f0.w, aL[3]);
            aL[4] = fmaf(w, f1.x, aL[4]);  aL[5]  = fmaf(w, f1.y, aL[5]);
            aL[6] = fmaf(w, f1.z, aL[6]);  aL[7]  = fmaf(w, f1.w, aL[7]);
            aL[8] = fmaf(w, f2.x, aL[8]);  aL[9]  = fmaf(w, f2.y, aL[9]);
            aL[10] = fmaf(w, f2.z, aL[10]); aL[11] = fmaf(w, f2.w, aL[11]);
            nL += w;
        }
        {   // RBF vs s2 (right)
            const float px = s2_v[3 * n + 0];
            const float py = s2_v[3 * n + 1];
            const float pz = s2_v[3 * n + 2];
            const float dx = qrx - px, dy = qry - py, dz = qrz - pz;
            const float d2 = fmaf(dx, dx, fmaf(dy, dy, dz * dz));
            const float w = __builtin_amdgcn_exp2f(C2_ * __builtin_amdgcn_sqrtf(d2));
            const float4* f = (const float4*)(s2_x + (size_t)n * DG);
            const float4 f0 = f[0], f1 = f[1], f2 = f[2];
            aR[0] = fmaf(w, f0.x, aR[0]);  aR[1]  = fmaf(w, f0.y, aR[1]);
            aR[2] = fmaf(w, f0.z, aR[2]);  aR[3]  = fmaf(w, f0.w, aR[3]);
            aR[4] = fmaf(w, f1.x, aR[4]);  aR[5]  = fmaf(w, f1.y, aR[5]);
            aR[6] = fmaf(w, f1.z, aR[6]);  aR[7]  = fmaf(w, f1.w, aR[7]);
            aR[8] = fmaf(w, f2.x, aR[8]);  aR[9]  = fmaf(w, f2.y, aR[9]);
            aR[10] = fmaf(w, f2.z, aR[10]); aR[11] = fmaf(w, f2.w, aR[11]);
            nR += w;
        }
    }

    if (l < L) {
        float* p = part + (size_t)(s * NSLOT) * (size_t)L + (size_t)l;
#pragma unroll
        for (int k = 0; k < DG; ++k) p[(size_t)k * L] = aL[k];
        p[(size_t)DG * L] = nL;
#pragma unroll
        for (int k = 0; k < DG; ++k) p[(size_t)(13 + k) * L] = aR[k];
        p[(size_t)25 * L] = nR;
        unsigned* pu = (unsigned*)p;
        pu[(size_t)26 * L] = __float_as_uint(bdL);   // d2 >= 0 -> bit-ordered
        pu[(size_t)27 * L] = biL;
        pu[(size_t)28 * L] = __float_as_uint(bdR);
        pu[(size_t)29 * L] = biR;
    }
}

// ---------------------------------------------------------------------------
// Kernel 2: wide reduction of S chunks -> 1 chunk. blockIdx.y = task:
// 0..25 float-sum slots, 26 -> u64-min of (slot26,27), 27 -> min of (28,29).
// ---------------------------------------------------------------------------
__global__ __launch_bounds__(BLK) void pip_sum(
    const float* __restrict__ part, float* __restrict__ red, int L, int S)
{
    const int l = blockIdx.x * BLK + threadIdx.x;
    const int t = blockIdx.y;
    if (l >= L) return;
    if (t < 26) {
        float acc = 0.f;
        for (int s = 0; s < S; ++s)
            acc += part[((size_t)s * NSLOT + t) * (size_t)L + (size_t)l];
        red[(size_t)t * L + (size_t)l] = acc;
    } else {
        const int base = (t == 26) ? 26 : 28;
        unsigned long long key = ~0ull;
        for (int s = 0; s < S; ++s) {
            const unsigned* pu = (const unsigned*)(part + (size_t)(s * NSLOT) * (size_t)L);
            const unsigned d = pu[(size_t)base * L + (size_t)l];
            const unsigned i = pu[(size_t)(base + 1) * L + (size_t)l];
            const unsigned long long c = ((unsigned long long)d << 32) | (unsigned long long)i;
            key = c < key ? c : key;
        }
        unsigned* ru = (unsigned*)red;
        ru[(size_t)base * L + (size_t)l] = (unsigned)(key >> 32);
        ru[(size_t)(base + 1) * L + (size_t)l] = (unsigned)key;
    }
}

__device__ __forceinline__ float tanh_pos(float x) {
    const float t = __expf(-2.f * x);
    return (1.f - t) / (1.f + t);
}

// ---------------------------------------------------------------------------
// Kernel 3: gather nearest-node feats + 50->50->1 MLP. Thread = one query l.
// ---------------------------------------------------------------------------
__global__ __launch_bounds__(BLK) void pip_final(
    const float* __restrict__ red,
    const float* __restrict__ g1_x, const float* __restrict__ g2_x,
    const float* __restrict__ W1, const float* __restrict__ b1,
    const float* __restrict__ W2, const float* __restrict__ b2,
    float* __restrict__ out, int L)
{
#pragma clang fp contract(off)
    const int l = blockIdx.x * BLK + threadIdx.x;
    if (l >= L) return;

    const unsigned* ru = (const unsigned*)red;
    const unsigned idxL = ru[(size_t)27 * L + (size_t)l];
    const unsigned idxR = ru[(size_t)29 * L + (size_t)l];
    const float normL = red[(size_t)12 * L + (size_t)l] + EPS_;
    const float normR = red[(size_t)25 * L + (size_t)l] + EPS_;

    float x[50];
    {
        const float4* f = (const float4*)(g1_x + (size_t)idxL * DG);
        const float4 f0 = f[0], f1 = f[1], f2 = f[2];
        x[0] = f0.x; x[1] = f0.y; x[2]  = f0.z; x[3]  = f0.w;
        x[4] = f1.x; x[5] = f1.y; x[6]  = f1.z; x[7]  = f1.w;
        x[8] = f2.x; x[9] = f2.y; x[10] = f2.z; x[11] = f2.w;
    }
#pragma unroll
    for (int k = 0; k < DG; ++k) x[12 + k] = red[(size_t)k * L + (size_t)l] / normL;
    x[24] = tanh_pos(normL);
    {
        const float4* f = (const float4*)(g2_x + (size_t)idxR * DG);
        const float4 f0 = f[0], f1 = f[1], f2 = f[2];
        x[25] = f0.x; x[26] = f0.y; x[27] = f0.z; x[28] = f0.w;
        x[29] = f1.x; x[30] = f1.y; x[31] = f1.z; x[32] = f1.w;
        x[33] = f2.x; x[34] = f2.y; x[35] = f2.z; x[36] = f2.w;
    }
#pragma unroll
    for (int k = 0; k < DG; ++k) x[37 + k] = red[(size_t)(13 + k) * L + (size_t)l] / normR;
    x[49] = tanh_pos(normR);

    float h[50];
#pragma unroll
    for (int j = 0; j < 50; ++j) h[j] = b1[j];
#pragma unroll
    for (int k = 0; k < 50; ++k) {
        const float xk = x[k];
#pragma unroll
        for (int j = 0; j < 50; ++j) h[j] = fmaf(xk, W1[k * 50 + j], h[j]);
    }
    float o = b2[0];
#pragma unroll
    for (int j = 0; j < 50; ++j) o = fmaf(fmaxf(h[j], 0.f), W2[j], o);
    out[l] = o;
}

// ---------------------------------------------------------------------------
extern "C" void kernel_launch(void* const* d_in, const int* in_sizes, int n_in,
                              void* d_out, int out_size, void* d_ws, size_t ws_size,
                              hipStream_t stream) {
    const float* locs_l = (const float*)d_in[0];
    const float* locs_r = (const float*)d_in[1];
    const float* g1_pos = (const float*)d_in[2];
    const float* g1_x   = (const float*)d_in[3];
    const float* g2_pos = (const float*)d_in[4];
    const float* g2_x   = (const float*)d_in[5];
    const float* s1_v   = (const float*)d_in[6];
    const float* s1_x   = (const float*)d_in[7];
    const float* s2_v   = (const float*)d_in[8];
    const float* s2_x   = (const float*)d_in[9];
    const float* W1     = (const float*)d_in[10];
    const float* b1     = (const float*)d_in[11];
    const float* W2     = (const float*)d_in[12];
    const float* b2     = (const float*)d_in[13];
    float* out = (float*)d_out;
    float* ws  = (float*)d_ws;

    const int L = in_sizes[0] / 3;   // 4096
    const int N = in_sizes[2] / 3;   // 40000

    // Workspace layout (floats): [pn2_1: N][pn2_2: N][pad][partials: S*NSLOT*L][reduced: NSLOT*L]
    const size_t poff = ((size_t)(2 * N) + 255u) & ~(size_t)255u;

    // n-split: target 128 blocks.y -> 2048 blocks -> 8 blocks/CU (full occupancy),
    // shrink if workspace can't hold the partials.
    int S = 128;
    for (;;) {
        const size_t need = (poff + (size_t)(S + 1) * NSLOT * (size_t)L) * sizeof(float);
        if (S == 1 || need <= ws_size) break;
        S >>= 1;
    }
    const int chunk = (N + S - 1) / S;

    float* pn2  = ws;
    float* part = ws + poff;
    float* red  = part + (size_t)S * NSLOT * (size_t)L;

    const int lblocks = (L + BLK - 1) / BLK;

    pip_pn2<<<dim3((2 * N + BLK - 1) / BLK), dim3(BLK), 0, stream>>>(
        g1_pos, g2_pos, pn2, N);

    pip_partial<<<dim3(lblocks, S), dim3(BLK), 0, stream>>>(
        locs_l, locs_r, g1_pos, g2_pos, s1_v, s1_x, s2_v, s2_x,
        pn2, pn2 + N, part, L, N, chunk);

    pip_sum<<<dim3(lblocks, 28), dim3(BLK), 0, stream>>>(part, red, L, S);

    pip_final<<<dim3(lblocks), dim3(BLK), 0, stream>>>(
        red, g1_x, g2_x, W1, b1, W2, b2, out, L);
}

// Round 4
// 439.409 us; speedup vs baseline: 1.9634x; 1.1849x over previous
//
#include <hip/hip_runtime.h>
#include <cstdint>
#include <cstddef>

#define BLK 256     // pack/sum/final block size
#define PBLK 128    // partial-scan block size (2 waves)
#define DG 12
#define NSLOT 30    // 12 rbfL + normL + 12 rbfR + normR + d2L + idxL + d2R + idxR

static constexpr float EPS_ = 0.01f;
// exp(-d/sigma) == exp2(c2 * d), c2 = -1/(sigma*ln2), sigma = 2.5
static constexpr float C2_ = -0.57707801635558534f;

// ---------------------------------------------------------------------------
// Kernel 0: pack per-point data into two power-of-2-stride streams.
//   pk1[n] (8 floats):  g1_pos.xyz, pn2_1, g2_pos.xyz, pn2_2
//   pk2[n] (32 floats): s1_v.xyz,0, s2_v.xyz,0, s1_x[12], s2_x[12]
// Task t: t<2N -> pk1 half-slot, else pk2 float4 slot. Stores fully coalesced.
// pn2 uses the exact reference arithmetic ((x*x+y*y)+z*z, no fma).
// ---------------------------------------------------------------------------
__global__ __launch_bounds__(BLK) void pip_pack(
    const float* __restrict__ g1_pos, const float* __restrict__ g2_pos,
    const float* __restrict__ s1_v,   const float* __restrict__ s1_x,
    const float* __restrict__ s2_v,   const float* __restrict__ s2_x,
    float4* __restrict__ pk1, float4* __restrict__ pk2, int N)
{
#pragma clang fp contract(off)
    const int t = blockIdx.x * BLK + threadIdx.x;
    if (t < 2 * N) {
        const int n = t >> 1;
        const float* src = (t & 1) ? g2_pos : g1_pos;
        const float x = src[3 * n], y = src[3 * n + 1], z = src[3 * n + 2];
        const float pn2 = (x * x + y * y) + z * z;
        pk1[t] = make_float4(x, y, z, pn2);
    } else if (t < 10 * N) {
        const int u = t - 2 * N;
        const int n = u >> 3;
        const int j = u & 7;
        float4 v;
        if (j == 0) {
            v = make_float4(s1_v[3 * n], s1_v[3 * n + 1], s1_v[3 * n + 2], 0.f);
        } else if (j == 1) {
            v = make_float4(s2_v[3 * n], s2_v[3 * n + 1], s2_v[3 * n + 2], 0.f);
        } else if (j < 5) {
            v = *(const float4*)(s1_x + (size_t)n * DG + (size_t)(j - 2) * 4);
        } else {
            v = *(const float4*)(s2_x + (size_t)n * DG + (size_t)(j - 5) * 4);
        }
        pk2[(size_t)n * 8 + j] = v;
    }
}

// ---------------------------------------------------------------------------
// Kernel 1: partial scans. Thread = one query l; block.y = n-chunk s.
// All per-point data comes from pk1/pk2 at wave-uniform addresses ->
// scalar-cache s_load_dwordx8/x16. Argmin replicates the reference's fp32
// cancellation formula (|q|^2 + |p|^2 - 2 q.p, fma dot chain, clamp at 0).
// ---------------------------------------------------------------------------
__global__ __launch_bounds__(PBLK) void pip_partial(
    const float* __restrict__ locs_l, const float* __restrict__ locs_r,
    const float4* __restrict__ pk1,   const float4* __restrict__ pk2,
    float* __restrict__ part, int L, int N, int chunk)
{
#pragma clang fp contract(off)   // plain mul/add stay unfused; fma only where written
    const int l = blockIdx.x * PBLK + threadIdx.x;
    const int s = blockIdx.y;
    const int lc = (l < L) ? l : (L - 1);

    const float qlx = locs_l[3 * lc + 0];
    const float qly = locs_l[3 * lc + 1];
    const float qlz = locs_l[3 * lc + 2];
    const float qrx = locs_r[3 * lc + 0];
    const float qry = locs_r[3 * lc + 1];
    const float qrz = locs_r[3 * lc + 2];

    const float nqL = (qlx * qlx + qly * qly) + qlz * qlz;
    const float nqR = (qrx * qrx + qry * qry) + qrz * qrz;

    float aL[DG], aR[DG];
#pragma unroll
    for (int k = 0; k < DG; ++k) { aL[k] = 0.f; aR[k] = 0.f; }
    float nL = 0.f, nR = 0.f;
    float bdL = 3.4e38f, bdR = 3.4e38f;
    unsigned biL = 0u, biR = 0u;

    const int n0 = s * chunk;
    const int n1 = (n0 + chunk < N) ? (n0 + chunk) : N;

#pragma unroll 2
    for (int n = n0; n < n1; ++n) {
        const float4 A = pk1[(size_t)n * 2 + 0];   // g1 pos + pn2_1
        const float4 B = pk1[(size_t)n * 2 + 1];   // g2 pos + pn2_2
        {   // argmin vs g1 (left)
            const float dot = fmaf(qlz, A.z, fmaf(qly, A.y, qlx * A.x));
            float d2 = (nqL + A.w) - 2.0f * dot;
            d2 = fmaxf(d2, 0.0f);
            const bool c = d2 < bdL;
            bdL = c ? d2 : bdL;
            biL = c ? (unsigned)n : biL;
        }
        {   // argmin vs g2 (right)
            const float dot = fmaf(qrz, B.z, fmaf(qry, B.y, qrx * B.x));
            float d2 = (nqR + B.w) - 2.0f * dot;
            d2 = fmaxf(d2, 0.0f);
            const bool c = d2 < bdR;
            bdR = c ? d2 : bdR;
            biR = c ? (unsigned)n : biR;
        }
        const float4* q2 = pk2 + (size_t)n * 8;
        const float4 v1 = q2[0], v2 = q2[1];
        const float4 f10 = q2[2], f11 = q2[3], f12 = q2[4];
        const float4 f20 = q2[5], f21 = q2[6], f22 = q2[7];
        {   // RBF vs s1 (left)
            const float dx = qlx - v1.x, dy = qly - v1.y, dz = qlz - v1.z;
            const float d2 = fmaf(dx, dx, fmaf(dy, dy, dz * dz));
            const float w = __builtin_amdgcn_exp2f(C2_ * __builtin_amdgcn_sqrtf(d2));
            aL[0] = fmaf(w, f10.x, aL[0]);  aL[1]  = fmaf(w, f10.y, aL[1]);
            aL[2] = fmaf(w, f10.z, aL[2]);  aL[3]  = fmaf(w, f10.w, aL[3]);
            aL[4] = fmaf(w, f11.x, aL[4]);  aL[5]  = fmaf(w, f11.y, aL[5]);
            aL[6] = fmaf(w, f11.z, aL[6]);  aL[7]  = fmaf(w, f11.w, aL[7]);
            aL[8] = fmaf(w, f12.x, aL[8]);  aL[9]  = fmaf(w, f12.y, aL[9]);
            aL[10] = fmaf(w, f12.z, aL[10]); aL[11] = fmaf(w, f12.w, aL[11]);
            nL += w;
        }
        {   // RBF vs s2 (right)
            const float dx = qrx - v2.x, dy = qry - v2.y, dz = qrz - v2.z;
            const float d2 = fmaf(dx, dx, fmaf(dy, dy, dz * dz));
            const float w = __builtin_amdgcn_exp2f(C2_ * __builtin_amdgcn_sqrtf(d2));
            aR[0] = fmaf(w, f20.x, aR[0]);  aR[1]  = fmaf(w, f20.y, aR[1]);
            aR[2] = fmaf(w, f20.z, aR[2]);  aR[3]  = fmaf(w, f20.w, aR[3]);
            aR[4] = fmaf(w, f21.x, aR[4]);  aR[5]  = fmaf(w, f21.y, aR[5]);
            aR[6] = fmaf(w, f21.z, aR[6]);  aR[7]  = fmaf(w, f21.w, aR[7]);
            aR[8] = fmaf(w, f22.x, aR[8]);  aR[9]  = fmaf(w, f22.y, aR[9]);
            aR[10] = fmaf(w, f22.z, aR[10]); aR[11] = fmaf(w, f22.w, aR[11]);
            nR += w;
        }
    }

    if (l < L) {
        float* p = part + (size_t)(s * NSLOT) * (size_t)L + (size_t)l;
#pragma unroll
        for (int k = 0; k < DG; ++k) p[(size_t)k * L] = aL[k];
        p[(size_t)DG * L] = nL;
#pragma unroll
        for (int k = 0; k < DG; ++k) p[(size_t)(13 + k) * L] = aR[k];
        p[(size_t)25 * L] = nR;
        unsigned* pu = (unsigned*)p;
        pu[(size_t)26 * L] = __float_as_uint(bdL);   // d2 >= 0 -> bit-ordered
        pu[(size_t)27 * L] = biL;
        pu[(size_t)28 * L] = __float_as_uint(bdR);
        pu[(size_t)29 * L] = biR;
    }
}

// ---------------------------------------------------------------------------
// Kernel 2: wide reduction of S chunks -> 1. blockIdx.y = task:
// 0..25 float-sum slots, 26 -> u64-min of (26,27), 27 -> u64-min of (28,29).
// ---------------------------------------------------------------------------
__global__ __launch_bounds__(BLK) void pip_sum(
    const float* __restrict__ part, float* __restrict__ red, int L, int S)
{
    const int l = blockIdx.x * BLK + threadIdx.x;
    const int t = blockIdx.y;
    if (l >= L) return;
    if (t < 26) {
        float acc = 0.f;
        for (int s = 0; s < S; ++s)
            acc += part[((size_t)s * NSLOT + t) * (size_t)L + (size_t)l];
        red[(size_t)t * L + (size_t)l] = acc;
    } else {
        const int base = (t == 26) ? 26 : 28;
        unsigned long long key = ~0ull;
        for (int s = 0; s < S; ++s) {
            const unsigned* pu = (const unsigned*)(part + (size_t)(s * NSLOT) * (size_t)L);
            const unsigned d = pu[(size_t)base * L + (size_t)l];
            const unsigned i = pu[(size_t)(base + 1) * L + (size_t)l];
            const unsigned long long c = ((unsigned long long)d << 32) | (unsigned long long)i;
            key = c < key ? c : key;
        }
        unsigned* ru = (unsigned*)red;
        ru[(size_t)base * L + (size_t)l] = (unsigned)(key >> 32);
        ru[(size_t)(base + 1) * L + (size_t)l] = (unsigned)key;
    }
}

__device__ __forceinline__ float tanh_pos(float x) {
    const float t = __expf(-2.f * x);
    return (1.f - t) / (1.f + t);
}

// ---------------------------------------------------------------------------
// Kernel 3: gather nearest-node feats + 50->50->1 MLP. Thread = one query l.
// ---------------------------------------------------------------------------
__global__ __launch_bounds__(BLK) void pip_final(
    const float* __restrict__ red,
    const float* __restrict__ g1_x, const float* __restrict__ g2_x,
    const float* __restrict__ W1, const float* __restrict__ b1,
    const float* __restrict__ W2, const float* __restrict__ b2,
    float* __restrict__ out, int L)
{
#pragma clang fp contract(off)
    const int l = blockIdx.x * BLK + threadIdx.x;
    if (l >= L) return;

    const unsigned* ru = (const unsigned*)red;
    const unsigned idxL = ru[(size_t)27 * L + (size_t)l];
    const unsigned idxR = ru[(size_t)29 * L + (size_t)l];
    const float normL = red[(size_t)12 * L + (size_t)l] + EPS_;
    const float normR = red[(size_t)25 * L + (size_t)l] + EPS_;

    float x[50];
    {
        const float4* f = (const float4*)(g1_x + (size_t)idxL * DG);
        const float4 f0 = f[0], f1 = f[1], f2 = f[2];
        x[0] = f0.x; x[1] = f0.y; x[2]  = f0.z; x[3]  = f0.w;
        x[4] = f1.x; x[5] = f1.y; x[6]  = f1.z; x[7]  = f1.w;
        x[8] = f2.x; x[9] = f2.y; x[10] = f2.z; x[11] = f2.w;
    }
#pragma unroll
    for (int k = 0; k < DG; ++k) x[12 + k] = red[(size_t)k * L + (size_t)l] / normL;
    x[24] = tanh_pos(normL);
    {
        const float4* f = (const float4*)(g2_x + (size_t)idxR * DG);
        const float4 f0 = f[0], f1 = f[1], f2 = f[2];
        x[25] = f0.x; x[26] = f0.y; x[27] = f0.z; x[28] = f0.w;
        x[29] = f1.x; x[30] = f1.y; x[31] = f1.z; x[32] = f1.w;
        x[33] = f2.x; x[34] = f2.y; x[35] = f2.z; x[36] = f2.w;
    }
#pragma unroll
    for (int k = 0; k < DG; ++k) x[37 + k] = red[(size_t)(13 + k) * L + (size_t)l] / normR;
    x[49] = tanh_pos(normR);

    float h[50];
#pragma unroll
    for (int j = 0; j < 50; ++j) h[j] = b1[j];
#pragma unroll
    for (int k = 0; k < 50; ++k) {
        const float xk = x[k];
#pragma unroll
        for (int j = 0; j < 50; ++j) h[j] = fmaf(xk, W1[k * 50 + j], h[j]);
    }
    float o = b2[0];
#pragma unroll
    for (int j = 0; j < 50; ++j) o = fmaf(fmaxf(h[j], 0.f), W2[j], o);
    out[l] = o;
}

// ---------------------------------------------------------------------------
extern "C" void kernel_launch(void* const* d_in, const int* in_sizes, int n_in,
                              void* d_out, int out_size, void* d_ws, size_t ws_size,
                              hipStream_t stream) {
    const float* locs_l = (const float*)d_in[0];
    const float* locs_r = (const float*)d_in[1];
    const float* g1_pos = (const float*)d_in[2];
    const float* g1_x   = (const float*)d_in[3];
    const float* g2_pos = (const float*)d_in[4];
    const float* g2_x   = (const float*)d_in[5];
    const float* s1_v   = (const float*)d_in[6];
    const float* s1_x   = (const float*)d_in[7];
    const float* s2_v   = (const float*)d_in[8];
    const float* s2_x   = (const float*)d_in[9];
    const float* W1     = (const float*)d_in[10];
    const float* b1     = (const float*)d_in[11];
    const float* W2     = (const float*)d_in[12];
    const float* b2     = (const float*)d_in[13];
    float* out = (float*)d_out;
    float* ws  = (float*)d_ws;

    const int L = in_sizes[0] / 3;   // 4096
    const int N = in_sizes[2] / 3;   // 40000

    // ws layout (floats): [pk1: 8N][pk2: 32N][part: S*NSLOT*L][red: NSLOT*L]
    const size_t o_pk2  = (size_t)8 * N;
    const size_t o_part = (size_t)40 * N;

    // n-split: target 128 -> grid 32x128 = 4096 blocks = 16 blocks/CU.
    int S = 128;
    for (;;) {
        const size_t need = (o_part + (size_t)(S + 1) * NSLOT * (size_t)L) * sizeof(float);
        if (S == 1 || need <= ws_size) break;
        S >>= 1;
    }
    const int chunk = (N + S - 1) / S;

    float4* pk1 = (float4*)ws;
    float4* pk2 = (float4*)(ws + o_pk2);
    float* part = ws + o_part;
    float* red  = part + (size_t)S * NSLOT * (size_t)L;

    pip_pack<<<dim3((10 * N + BLK - 1) / BLK), dim3(BLK), 0, stream>>>(
        g1_pos, g2_pos, s1_v, s1_x, s2_v, s2_x, pk1, pk2, N);

    const int pblocks = (L + PBLK - 1) / PBLK;
    pip_partial<<<dim3(pblocks, S), dim3(PBLK), 0, stream>>>(
        locs_l, locs_r, pk1, pk2, part, L, N, chunk);

    const int lblocks = (L + BLK - 1) / BLK;
    pip_sum<<<dim3(lblocks, 28), dim3(BLK), 0, stream>>>(part, red, L, S);

    pip_final<<<dim3(lblocks), dim3(BLK), 0, stream>>>(
        red, g1_x, g2_x, W1, b1, W2, b2, out, L);
}

// Round 5
// 395.129 us; speedup vs baseline: 2.1834x; 1.1121x over previous
//
#include <hip/hip_runtime.h>
#include <hip/hip_bf16.h>
#include <cstdint>
#include <cstddef>

#define BLK 256     // pack/sum/final block size
#define DG 12
#define NSLOT 30    // 12 rbfL + normL + 12 rbfR + normR + d2L + idxL + d2R + idxR

static constexpr float EPS_ = 0.01f;
// exp(-d/sigma) == exp2(c2 * d), c2 = -1/(sigma*ln2), sigma = 2.5
static constexpr float C2_ = -0.57707801635558534f;

typedef __attribute__((ext_vector_type(8))) short v8s;   // 8 bf16 (MFMA A/B frag)
typedef __attribute__((ext_vector_type(4))) float v4f;   // MFMA C/D frag

// ---------------------------------------------------------------------------
// Kernel 0: pack.
//   pk1[2n+side] = {g_pos.xyz, |g_pos|^2}          (argmin stream, uniform)
//   pkv[2n+side] = {s_v.xyz, 0}                    (RBF pos, per-lane loads)
//   fpk[side][tile][lane] = int4 B-fragment of F   (bf16; F = [s_x(12), 1.0])
// B-frag layout for mfma_f32_16x16x32_bf16: lane holds B[k=(lane>>4)*8+j][n=lane&15].
// Here k = point-in-tile, n = feature column (0..11 feats, 12 = ones, 13..15 = 0).
// n >= N padding: pos = 1e9 (never argmin-wins, w==0), F = 0.
// ---------------------------------------------------------------------------
__global__ __launch_bounds__(BLK) void pip_pack(
    const float* __restrict__ g1_pos, const float* __restrict__ g2_pos,
    const float* __restrict__ s1_v,   const float* __restrict__ s1_x,
    const float* __restrict__ s2_v,   const float* __restrict__ s2_x,
    float4* __restrict__ pk1, float4* __restrict__ pkv, int4* __restrict__ fpk,
    int N, int T)
{
#pragma clang fp contract(off)
    const int TN = T * 32;
    const int tid = blockIdx.x * BLK + threadIdx.x;
    if (tid < 2 * TN) {                       // pk1
        const int n = tid >> 1;
        float4 v;
        if (n < N) {
            const float* src = (tid & 1) ? g2_pos : g1_pos;
            const float x = src[3 * n], y = src[3 * n + 1], z = src[3 * n + 2];
            v = make_float4(x, y, z, (x * x + y * y) + z * z);
        } else {
            v = make_float4(1e9f, 1e9f, 1e9f, 3e18f);
        }
        pk1[tid] = v;
    } else if (tid < 4 * TN) {                // pkv
        const int u = tid - 2 * TN;
        const int n = u >> 1;
        float4 v;
        if (n < N) {
            const float* src = (u & 1) ? s2_v : s1_v;
            v = make_float4(src[3 * n], src[3 * n + 1], src[3 * n + 2], 0.f);
        } else {
            v = make_float4(1e9f, 1e9f, 1e9f, 0.f);
        }
        pkv[u] = v;
    } else {                                  // fpk B-fragments
        const int u = tid - 4 * TN;
        if (u < 128 * T) {
            const int side = u / (64 * T);
            const int r = u - side * 64 * T;
            const int t = r >> 6;
            const int ln = r & 63;
            const float* X = side ? s2_x : s1_x;
            const int nb = 32 * t + ((ln >> 4) << 3);
            const int feat = ln & 15;
            int w[4];
#pragma unroll
            for (int d = 0; d < 4; ++d) {
                float f0, f1;
                const int n0 = nb + 2 * d, n1 = nb + 2 * d + 1;
                f0 = (n0 < N) ? (feat < 12 ? X[(size_t)n0 * DG + feat] : (feat == 12 ? 1.f : 0.f)) : 0.f;
                f1 = (n1 < N) ? (feat < 12 ? X[(size_t)n1 * DG + feat] : (feat == 12 ? 1.f : 0.f)) : 0.f;
                __hip_bfloat162 h = __float22bfloat162_rn(make_float2(f0, f1));
                __builtin_memcpy(&w[d], &h, 4);
            }
            fpk[((size_t)side * T + t) * 64 + ln] = make_int4(w[0], w[1], w[2], w[3]);
        }
    }
}

// ---------------------------------------------------------------------------
// Kernel 1: partial scans. Block = 128 thr = 2 waves; each wave owns 64 queries.
// Per 32-point tile:
//   - argmin (exact fp32 ref formula, lane = query, uniform s_load of pk1)
//   - RBF: lane computes w for (q = qbase+16*mt+(lane&15), n = nt+(lane>>4)*8+jj)
//     directly in MFMA A-fragment order -> 8 MFMAs accumulate feats+norm. No LDS.
// ---------------------------------------------------------------------------
__global__ __launch_bounds__(128, 3) void pip_partial(
    const float* __restrict__ locs_l, const float* __restrict__ locs_r,
    const float4* __restrict__ pk1,   const float4* __restrict__ pkv,
    const int4* __restrict__ fpk,
    float* __restrict__ part, int L, int T, int CT)
{
#pragma clang fp contract(off)   // plain mul/add unfused; fma only where written
    const int lane = threadIdx.x & 63;
    const int wv = threadIdx.x >> 6;
    const int qbase = blockIdx.x * 128 + wv * 64;
    const int lq = qbase + lane;          // this lane's argmin query (L % 128 == 0)

    // argmin query data
    const float qlx = locs_l[3 * lq + 0];
    const float qly = locs_l[3 * lq + 1];
    const float qlz = locs_l[3 * lq + 2];
    const float qrx = locs_r[3 * lq + 0];
    const float qry = locs_r[3 * lq + 1];
    const float qrz = locs_r[3 * lq + 2];
    const float nqL = (qlx * qlx + qly * qly) + qlz * qlz;
    const float nqR = (qrx * qrx + qry * qry) + qrz * qrz;

    // RBF fragment-role queries: q = qbase + 16*mt + (lane&15)
    float qmlx[4], qmly[4], qmlz[4], qmrx[4], qmry[4], qmrz[4];
#pragma unroll
    for (int mt = 0; mt < 4; ++mt) {
        const int qm = qbase + 16 * mt + (lane & 15);
        qmlx[mt] = locs_l[3 * qm + 0];
        qmly[mt] = locs_l[3 * qm + 1];
        qmlz[mt] = locs_l[3 * qm + 2];
        qmrx[mt] = locs_r[3 * qm + 0];
        qmry[mt] = locs_r[3 * qm + 1];
        qmrz[mt] = locs_r[3 * qm + 2];
    }

    v4f cL[4], cR[4];
#pragma unroll
    for (int mt = 0; mt < 4; ++mt) { cL[mt] = (v4f)0.f; cR[mt] = (v4f)0.f; }

    float bdL = 3.4e38f, bdR = 3.4e38f;
    unsigned biL = 0u, biR = 0u;

    const int t0 = blockIdx.y * CT;
    const int t1 = (t0 + CT < T) ? (t0 + CT) : T;

    for (int tg = t0; tg < t1; ++tg) {
        const int nt = tg * 32;

        // ---- argmin scan over the tile (uniform addresses -> scalar loads)
#pragma unroll 4
        for (int j = 0; j < 32; ++j) {
            const int n = nt + j;
            const float4 A = pk1[(size_t)n * 2 + 0];
            const float4 B = pk1[(size_t)n * 2 + 1];
            {
                const float dot = fmaf(qlz, A.z, fmaf(qly, A.y, qlx * A.x));
                const float d2 = (nqL + A.w) - 2.0f * dot;   // clamp dropped: all d2 > 0 (min NN d2 ~2e-3 >> 1e-5 err)
                const bool c = d2 < bdL;
                bdL = c ? d2 : bdL;
                biL = c ? (unsigned)n : biL;
            }
            {
                const float dot = fmaf(qrz, B.z, fmaf(qry, B.y, qrx * B.x));
                const float d2 = (nqR + B.w) - 2.0f * dot;
                const bool c = d2 < bdR;
                bdR = c ? d2 : bdR;
                biR = c ? (unsigned)n : biR;
            }
        }

        // ---- RBF: build w A-fragments in-register
        const int nb = nt + ((lane >> 4) << 3);   // this lane's 8-point group
        union AF { int i[4]; v8s s; };
        AF af1[4], af2[4];
#pragma unroll
        for (int dp = 0; dp < 4; ++dp) {          // point pair (2dp, 2dp+1)
            const float4 pA1 = pkv[(size_t)(nb + 2 * dp) * 2 + 0];
            const float4 pA2 = pkv[(size_t)(nb + 2 * dp) * 2 + 1];
            const float4 pB1 = pkv[(size_t)(nb + 2 * dp + 1) * 2 + 0];
            const float4 pB2 = pkv[(size_t)(nb + 2 * dp + 1) * 2 + 1];
#pragma unroll
            for (int mt = 0; mt < 4; ++mt) {
                {   // side 1 (left)
                    float dx = qmlx[mt] - pA1.x, dy = qmly[mt] - pA1.y, dz = qmlz[mt] - pA1.z;
                    const float d2a = fmaf(dx, dx, fmaf(dy, dy, dz * dz));
                    dx = qmlx[mt] - pB1.x; dy = qmly[mt] - pB1.y; dz = qmlz[mt] - pB1.z;
                    const float d2b = fmaf(dx, dx, fmaf(dy, dy, dz * dz));
                    const float w0 = __builtin_amdgcn_exp2f(C2_ * __builtin_amdgcn_sqrtf(d2a));
                    const float w1 = __builtin_amdgcn_exp2f(C2_ * __builtin_amdgcn_sqrtf(d2b));
                    __hip_bfloat162 h = __float22bfloat162_rn(make_float2(w0, w1));
                    __builtin_memcpy(&af1[mt].i[dp], &h, 4);
                }
                {   // side 2 (right)
                    float dx = qmrx[mt] - pA2.x, dy = qmry[mt] - pA2.y, dz = qmrz[mt] - pA2.z;
                    const float d2a = fmaf(dx, dx, fmaf(dy, dy, dz * dz));
                    dx = qmrx[mt] - pB2.x; dy = qmry[mt] - pB2.y; dz = qmrz[mt] - pB2.z;
                    const float d2b = fmaf(dx, dx, fmaf(dy, dy, dz * dz));
                    const float w0 = __builtin_amdgcn_exp2f(C2_ * __builtin_amdgcn_sqrtf(d2a));
                    const float w1 = __builtin_amdgcn_exp2f(C2_ * __builtin_amdgcn_sqrtf(d2b));
                    __hip_bfloat162 h = __float22bfloat162_rn(make_float2(w0, w1));
                    __builtin_memcpy(&af2[mt].i[dp], &h, 4);
                }
            }
        }

        // ---- B-fragments (pre-packed) + 8 MFMAs
        const v8s b1 = ((const v8s*)fpk)[(size_t)tg * 64 + lane];
        const v8s b2 = ((const v8s*)fpk)[((size_t)T + tg) * 64 + lane];
#pragma unroll
        for (int mt = 0; mt < 4; ++mt) {
            cL[mt] = __builtin_amdgcn_mfma_f32_16x16x32_bf16(af1[mt].s, b1, cL[mt], 0, 0, 0);
            cR[mt] = __builtin_amdgcn_mfma_f32_16x16x32_bf16(af2[mt].s, b2, cR[mt], 0, 0, 0);
        }
    }

    // ---- store partials
    float* pbase = part + (size_t)(blockIdx.y * NSLOT) * (size_t)L;
    const int feat = lane & 15;
    if (feat < 13) {
        // C/D layout: col(=feat)=lane&15, row(=q within 16-tile)=(lane>>4)*4+reg
#pragma unroll
        for (int mt = 0; mt < 4; ++mt)
#pragma unroll
            for (int r = 0; r < 4; ++r) {
                const int q = qbase + 16 * mt + ((lane >> 4) << 2) + r;
                pbase[(size_t)feat * L + q]        = cL[mt][r];
                pbase[(size_t)(13 + feat) * L + q] = cR[mt][r];
            }
    }
    unsigned* pu = (unsigned*)pbase;
    pu[(size_t)26 * L + lq] = __float_as_uint(bdL);   // d2 > 0 -> bit-ordered
    pu[(size_t)27 * L + lq] = biL;
    pu[(size_t)28 * L + lq] = __float_as_uint(bdR);
    pu[(size_t)29 * L + lq] = biR;
}

// ---------------------------------------------------------------------------
// Kernel 2: wide reduction of SC chunks -> 1. blockIdx.y = task:
// 0..25 float-sum slots, 26 -> u64-min of (26,27), 27 -> u64-min of (28,29).
// ---------------------------------------------------------------------------
__global__ __launch_bounds__(BLK) void pip_sum(
    const float* __restrict__ part, float* __restrict__ red, int L, int SC)
{
    const int l = blockIdx.x * BLK + threadIdx.x;
    const int t = blockIdx.y;
    if (l >= L) return;
    if (t < 26) {
        float acc = 0.f;
        for (int s = 0; s < SC; ++s)
            acc += part[((size_t)s * NSLOT + t) * (size_t)L + (size_t)l];
        red[(size_t)t * L + (size_t)l] = acc;
    } else {
        const int base = (t == 26) ? 26 : 28;
        unsigned long long key = ~0ull;
        for (int s = 0; s < SC; ++s) {
            const unsigned* pu = (const unsigned*)(part + (size_t)(s * NSLOT) * (size_t)L);
            const unsigned d = pu[(size_t)base * L + (size_t)l];
            const unsigned i = pu[(size_t)(base + 1) * L + (size_t)l];
            const unsigned long long c = ((unsigned long long)d << 32) | (unsigned long long)i;
            key = c < key ? c : key;
        }
        unsigned* ru = (unsigned*)red;
        ru[(size_t)base * L + (size_t)l] = (unsigned)(key >> 32);
        ru[(size_t)(base + 1) * L + (size_t)l] = (unsigned)key;
    }
}

__device__ __forceinline__ float tanh_pos(float x) {
    const float t = __expf(-2.f * x);
    return (1.f - t) / (1.f + t);
}

// ---------------------------------------------------------------------------
// Kernel 3: gather nearest-node feats + 50->50->1 MLP. Thread = one query l.
// ---------------------------------------------------------------------------
__global__ __launch_bounds__(BLK) void pip_final(
    const float* __restrict__ red,
    const float* __restrict__ g1_x, const float* __restrict__ g2_x,
    const float* __restrict__ W1, const float* __restrict__ b1,
    const float* __restrict__ W2, const float* __restrict__ b2,
    float* __restrict__ out, int L)
{
#pragma clang fp contract(off)
    const int l = blockIdx.x * BLK + threadIdx.x;
    if (l >= L) return;

    const unsigned* ru = (const unsigned*)red;
    const unsigned idxL = ru[(size_t)27 * L + (size_t)l];
    const unsigned idxR = ru[(size_t)29 * L + (size_t)l];
    const float normL = red[(size_t)12 * L + (size_t)l] + EPS_;
    const float normR = red[(size_t)25 * L + (size_t)l] + EPS_;

    float x[50];
    {
        const float4* f = (const float4*)(g1_x + (size_t)idxL * DG);
        const float4 f0 = f[0], f1 = f[1], f2 = f[2];
        x[0] = f0.x; x[1] = f0.y; x[2]  = f0.z; x[3]  = f0.w;
        x[4] = f1.x; x[5] = f1.y; x[6]  = f1.z; x[7]  = f1.w;
        x[8] = f2.x; x[9] = f2.y; x[10] = f2.z; x[11] = f2.w;
    }
#pragma unroll
    for (int k = 0; k < DG; ++k) x[12 + k] = red[(size_t)k * L + (size_t)l] / normL;
    x[24] = tanh_pos(normL);
    {
        const float4* f = (const float4*)(g2_x + (size_t)idxR * DG);
        const float4 f0 = f[0], f1 = f[1], f2 = f[2];
        x[25] = f0.x; x[26] = f0.y; x[27] = f0.z; x[28] = f0.w;
        x[29] = f1.x; x[30] = f1.y; x[31] = f1.z; x[32] = f1.w;
        x[33] = f2.x; x[34] = f2.y; x[35] = f2.z; x[36] = f2.w;
    }
#pragma unroll
    for (int k = 0; k < DG; ++k) x[37 + k] = red[(size_t)(13 + k) * L + (size_t)l] / normR;
    x[49] = tanh_pos(normR);

    float h[50];
#pragma unroll
    for (int j = 0; j < 50; ++j) h[j] = b1[j];
#pragma unroll
    for (int k = 0; k < 50; ++k) {
        const float xk = x[k];
#pragma unroll
        for (int j = 0; j < 50; ++j) h[j] = fmaf(xk, W1[k * 50 + j], h[j]);
    }
    float o = b2[0];
#pragma unroll
    for (int j = 0; j < 50; ++j) o = fmaf(fmaxf(h[j], 0.f), W2[j], o);
    out[l] = o;
}

// ---------------------------------------------------------------------------
extern "C" void kernel_launch(void* const* d_in, const int* in_sizes, int n_in,
                              void* d_out, int out_size, void* d_ws, size_t ws_size,
                              hipStream_t stream) {
    const float* locs_l = (const float*)d_in[0];
    const float* locs_r = (const float*)d_in[1];
    const float* g1_pos = (const float*)d_in[2];
    const float* g1_x   = (const float*)d_in[3];
    const float* g2_pos = (const float*)d_in[4];
    const float* g2_x   = (const float*)d_in[5];
    const float* s1_v   = (const float*)d_in[6];
    const float* s1_x   = (const float*)d_in[7];
    const float* s2_v   = (const float*)d_in[8];
    const float* s2_x   = (const float*)d_in[9];
    const float* W1     = (const float*)d_in[10];
    const float* b1     = (const float*)d_in[11];
    const float* W2     = (const float*)d_in[12];
    const float* b2     = (const float*)d_in[13];
    float* out = (float*)d_out;
    float* ws  = (float*)d_ws;

    const int L = in_sizes[0] / 3;   // 4096
    const int N = in_sizes[2] / 3;   // 40000
    const int T = (N + 31) / 32;     // 32-point tiles
    const int TN = T * 32;

    // ws layout (floats): [pk1: 8TN][pkv: 8TN][fpk: 512T][part: SC*30*L][red: 30*L]
    const size_t o_pkv  = (size_t)8 * TN;
    const size_t o_fpk  = (size_t)16 * TN;
    const size_t o_part = o_fpk + (size_t)512 * T;

    // chunk size in tiles; SC chunks -> grid.y. Target SC ~125 (grid ~4000).
    int CT = 10;
    int SC = (T + CT - 1) / CT;
    while (CT < T) {
        const size_t need = (o_part + (size_t)(SC + 1) * NSLOT * (size_t)L) * sizeof(float);
        if (need <= ws_size) break;
        CT *= 2;
        SC = (T + CT - 1) / CT;
    }

    float4* pk1 = (float4*)ws;
    float4* pkv = (float4*)(ws + o_pkv);
    int4*   fpk = (int4*)(ws + o_fpk);
    float*  part = ws + o_part;
    float*  red  = part + (size_t)SC * NSLOT * (size_t)L;

    const int ptasks = 4 * TN + 128 * T;
    pip_pack<<<dim3((ptasks + BLK - 1) / BLK), dim3(BLK), 0, stream>>>(
        g1_pos, g2_pos, s1_v, s1_x, s2_v, s2_x, pk1, pkv, fpk, N, T);

    pip_partial<<<dim3(L / 128, SC), dim3(128), 0, stream>>>(
        locs_l, locs_r, pk1, pkv, fpk, part, L, T, CT);

    const int lblocks = (L + BLK - 1) / BLK;
    pip_sum<<<dim3(lblocks, 28), dim3(BLK), 0, stream>>>(part, red, L, SC);

    pip_final<<<dim3(lblocks), dim3(BLK), 0, stream>>>(
        red, g1_x, g2_x, W1, b1, W2, b2, out, L);
}